// Round 7
// baseline (123.720 us; speedup 1.0000x reference)
//
#include <hip/hip_runtime.h>
#include <math.h>

typedef float v2f __attribute__((ext_vector_type(2)));

// Head-weight table transposed [c][hw] (float4 = {bw0,bw1,bw2,patc}) so the
// per-channel epilogue load is lane-coalesced (lane = pixel hw).
__device__ float4 g_wqt[131072];
// Conv weights pair-major: per channel-pair p: 27 tap-pairs, bias pair,
// match_w pair. Read with wave-uniform indices in the main kernel so the
// compiler can scalarize to s_load (SMEM pipe).
__device__ v2f g_cwt[64 * 29];

// ---------------------------------------------------------------------------
// Prep: build g_wqt (fused base+pat head, transposed) and g_cwt.
// ---------------------------------------------------------------------------
__global__ __launch_bounds__(256)
void prep_weights(const float* __restrict__ base_w,  // [131072,3]
                  const float* __restrict__ pat_w,   // [32768]
                  const int*   __restrict__ psi,     // [32]
                  const float* __restrict__ conv_w,  // [27,128]
                  const float* __restrict__ conv_b,  // [128]
                  const float* __restrict__ match_w) // [128]
{
    int idx = blockIdx.x * 256 + threadIdx.x;        // 0..131071
    int c = idx >> 10, hw = idx & 1023;
    const float* bp = base_w + ((size_t)hw * 128 + c) * 3;
    float pc = 0.f;
    const float* pr = pat_w + hw * 32;
    #pragma unroll
    for (int k = 0; k < 32; ++k)
        pc += (psi[k] == c) ? pr[k] : 0.f;
    g_wqt[idx] = make_float4(bp[0], bp[1], bp[2], pc);

    if (idx < 64 * 29) {
        int p = idx / 29, r = idx - p * 29;
        v2f v;
        if (r < 27)       v = (v2f){ conv_w[r * 128 + 2 * p], conv_w[r * 128 + 2 * p + 1] };
        else if (r == 27) v = (v2f){ conv_b[2 * p], conv_b[2 * p + 1] };
        else              v = (v2f){ match_w[2 * p], match_w[2 * p + 1] };
        g_cwt[idx] = v;
    }
}

// ---------------------------------------------------------------------------
// Main kernel: one block per sample, 1024 threads, THREAD = OUTPUT PIXEL
// (oh = tid>>5, ow = tid&31; all 1024 pixels in one pass, no spatial loop).
// x stencil (27 floats) loaded once into registers via 15 ds_read_b64.
// Channel loop (64 pairs): weights via uniform (scalar) loads from g_cwt,
// packed-fp32 FMAs, epilogue reads coalesced float4 pair from g_wqt.
// ---------------------------------------------------------------------------
__global__ __launch_bounds__(1024, 4)
void pattern_branch_kernel(const float* __restrict__ in,      // [B,64,64,3]
                           const float* __restrict__ match_b, // [1]
                           const float* __restrict__ pat_b,   // [1]
                           const float* __restrict__ base_b,  // [3]
                           float* __restrict__ out)           // [B,3]
{
    __shared__ float xf[65 * 200];       // padded image, 52 KB
    __shared__ float red[16][5];

    const int b   = blockIdx.x;
    const int tid = threadIdx.x;

    // ---- stage input: zero (covers SAME pad row 64 / col-tail), then fill
    float4* x4 = (float4*)xf;
    for (int s = tid; s < 65 * 50; s += 1024) x4[s] = make_float4(0.f, 0.f, 0.f, 0.f);
    __syncthreads();
    const float4* inp4 = (const float4*)(in + (size_t)b * 12288);
    for (int s = tid; s < 64 * 48; s += 1024) {     // 64 rows x 48 float4
        int r = s / 48;
        int q = s - r * 48;
        x4[r * 50 + q] = inp4[s];
    }
    __syncthreads();

    // ---- per-thread stencil: rows 2oh..2oh+2, floats 6ow..6ow+8 (+1 slack)
    const int oh = tid >> 5;
    const int ow = tid & 31;
    v2f xs[15];
    #pragma unroll
    for (int kh = 0; kh < 3; ++kh) {
        int rowoff = (2 * oh + kh) * 200 + 6 * ow;  // even -> 8B aligned
        #pragma unroll
        for (int u = 0; u < 5; ++u)
            xs[kh * 5 + u] = *(const v2f*)&xf[rowoff + 2 * u];
    }

    v2f sm2  = (v2f){0.f, 0.f};
    v2f sb01 = (v2f){0.f, 0.f};
    v2f sb2p = (v2f){0.f, 0.f};

    // ---- channel loop: 64 pairs
    for (int p = 0; p < 64; ++p) {
        const v2f* wp = g_cwt + p * 29;             // uniform -> s_load
        v2f accA = wp[27];                          // bias pair
        v2f accB = (v2f){0.f, 0.f};
        #pragma unroll
        for (int kh = 0; kh < 3; ++kh)
            #pragma unroll
            for (int t9 = 0; t9 < 9; ++t9) {
                float xv = xs[kh * 5 + (t9 >> 1)][t9 & 1];
                v2f wv = wp[kh * 9 + t9];
                if (t9 & 1) accB = __builtin_elementwise_fma((v2f){xv, xv}, wv, accB);
                else        accA = __builtin_elementwise_fma((v2f){xv, xv}, wv, accA);
            }
        v2f f2 = __builtin_elementwise_max(accA + accB, (v2f){0.f, 0.f});

        float4 wv0 = g_wqt[(2 * p) * 1024 + tid];   // coalesced (lane = hw)
        float4 wv1 = g_wqt[(2 * p + 1) * 1024 + tid];
        v2f mw2 = wp[28];
        sm2  = __builtin_elementwise_fma(mw2, f2, sm2);
        sb01 = __builtin_elementwise_fma((v2f){f2.x, f2.x}, (v2f){wv0.x, wv0.y}, sb01);
        sb01 = __builtin_elementwise_fma((v2f){f2.y, f2.y}, (v2f){wv1.x, wv1.y}, sb01);
        sb2p = __builtin_elementwise_fma((v2f){f2.x, f2.x}, (v2f){wv0.z, wv0.w}, sb2p);
        sb2p = __builtin_elementwise_fma((v2f){f2.y, f2.y}, (v2f){wv1.z, wv1.w}, sb2p);
    }

    // ---- reduction: wave shuffle then LDS across 16 waves
    float vals[5] = { sm2.x + sm2.y, sb01.x, sb01.y, sb2p.x, sb2p.y };
    #pragma unroll
    for (int off = 32; off > 0; off >>= 1)
        #pragma unroll
        for (int v = 0; v < 5; ++v)
            vals[v] += __shfl_down(vals[v], off, 64);
    int wv = tid >> 6, lane = tid & 63;
    if (lane == 0) {
        #pragma unroll
        for (int v = 0; v < 5; ++v) red[wv][v] = vals[v];
    }
    __syncthreads();
    if (tid == 0) {
        float t[5] = {0.f, 0.f, 0.f, 0.f, 0.f};
        for (int wj = 0; wj < 16; ++wj)
            #pragma unroll
            for (int v = 0; v < 5; ++v) t[v] += red[wj][v];
        float score = t[0] * (1.f / 1024.f) + match_b[0];
        float p = 1.f / (1.f + expf(-(t[4] + pat_b[0])));
        float l0 = t[1] + base_b[0], l1 = t[2] + base_b[1], l2 = t[3] + base_b[2];
        float m = fmaxf(l0, fmaxf(l1, l2));
        float e0 = expf(l0 - m), e1 = expf(l1 - m), e2 = expf(l2 - m);
        float inv = 1.f / (e0 + e1 + e2);
        bool use_pat = (score > 0.f) && (p >= 0.5f);
        float o0, o1, o2;
        if (use_pat) { o0 = p; o1 = 0.5f * (1.f - p); o2 = o1; }
        else         { o0 = e0 * inv; o1 = e1 * inv; o2 = e2 * inv; }
        out[b * 3 + 0] = o0;
        out[b * 3 + 1] = o1;
        out[b * 3 + 2] = o2;
    }
}

extern "C" void kernel_launch(void* const* d_in, const int* in_sizes, int n_in,
                              void* d_out, int out_size, void* d_ws, size_t ws_size,
                              hipStream_t stream) {
    const float* in      = (const float*)d_in[0];
    const float* conv_w  = (const float*)d_in[1];
    const float* conv_b  = (const float*)d_in[2];
    const float* match_w = (const float*)d_in[3];
    const float* match_b = (const float*)d_in[4];
    const float* pat_w   = (const float*)d_in[5];
    const float* pat_b   = (const float*)d_in[6];
    const float* base_w  = (const float*)d_in[7];
    const float* base_b  = (const float*)d_in[8];
    const int*   psi     = (const int*)d_in[9];
    float* out = (float*)d_out;

    (void)d_ws; (void)ws_size;  // workspace unused

    prep_weights<<<512, 256, 0, stream>>>(base_w, pat_w, psi, conv_w, conv_b, match_w);

    int B = in_sizes[0] / (64 * 64 * 3);   // 256
    pattern_branch_kernel<<<B, 1024, 0, stream>>>(
        in, match_b, pat_b, base_b, out);
}